// Round 6
// baseline (105533.667 us; speedup 1.0000x reference)
//
#include <hip/hip_runtime.h>
#include <cstdint>
#include <cstddef>

#define NN 50000
#define EE 300000
#define HH 64
#define PP 3
#define GG 50
#define LL 2
#define CAP 32
#define SLOPE 0.01f

__device__ __forceinline__ float lrelu(float x){ return x >= 0.f ? x : SLOPE*x; }

// gstart[g] = first index i with batch[i] >= g (batch sorted); gstart[GG] = NN
__global__ void k_bounds(const int* __restrict__ batch, int* __restrict__ gstart){
    int g = threadIdx.x;
    if (g > GG) return;
    int lo = 0, hi = NN;
    while (lo < hi){ int mid = (lo + hi) >> 1; if (batch[mid] < g) lo = mid + 1; else hi = mid; }
    gstart[g] = lo;
}

// Single-pass bucket-CSR fill over all 6 edge sets.
// bucket[(which*NN + row)*CAP + slot] = {col, bits(w)}
__global__ void k_fill2(const int* __restrict__ uei, const float* __restrict__ uew,
                        const int* __restrict__ fei, const float* __restrict__ few,
                        int* __restrict__ cnt, int2* __restrict__ bucket){
    int t = blockIdx.x * blockDim.x + threadIdx.x;
    if (t >= 2 * PP * EE) return;
    int which = t / EE;
    int e = t - which * EE;
    const int* ei; const float* ew; int p;
    if (which < PP){ ei = uei; ew = uew; p = which; }
    else           { ei = fei; ew = few; p = which - PP; }
    int row = ei[(size_t)(p * 2 + 0) * EE + e];
    int col = ei[(size_t)(p * 2 + 1) * EE + e];
    float w = ew[(size_t)p * EE + e];
    int slot = atomicAdd(cnt + (size_t)which * NN + row, 1);
    if (slot < CAP)
        bucket[((size_t)which * NN + row) * CAP + slot] = make_int2(col, __float_as_int(w));
}

// Register-blocked (N,64)@(64,64): 32 nodes/block, 4 waves, 8 nodes/wave, lane owns 1 column.
__global__ __launch_bounds__(256) void k_lin64(const float* __restrict__ X,
                       const float* __restrict__ W, const float* __restrict__ b,
                       float* __restrict__ out){
    __shared__ float xs[32][HH];
    int nb = blockIdx.x * 32;
    int t = threadIdx.x;
    #pragma unroll
    for (int i = 0; i < 2; ++i){
        int idx = t + 256 * i;
        int r = idx >> 4, c4 = idx & 15;
        int n = nb + r;
        float4 v = make_float4(0.f, 0.f, 0.f, 0.f);
        if (n < NN) v = *reinterpret_cast<const float4*>(X + (size_t)n * HH + c4 * 4);
        *reinterpret_cast<float4*>(&xs[r][c4 * 4]) = v;
    }
    __syncthreads();
    int lane = t & 63, wave = t >> 6, nw = wave * 8;
    float acc[8];
    float bb = b[lane];
    #pragma unroll
    for (int i = 0; i < 8; ++i) acc[i] = bb;
    #pragma unroll 2
    for (int k = 0; k < HH; ++k){
        float wv = W[(size_t)k * HH + lane];
        #pragma unroll
        for (int i = 0; i < 8; ++i) acc[i] += xs[nw + i][k] * wv;
    }
    #pragma unroll
    for (int i = 0; i < 8; ++i){
        int n = nb + nw + i;
        if (n < NN) out[(size_t)n * HH + lane] = acc[i];
    }
}

// Per-hop aggregation: wave per node; gather x_t[col] (256B coalesced) per edge,
// 7 accumulators: avg + 6 directional. Degree (sum w) computed inline.
// U row layout (448): [avg(64) | j=0..5: dir_j(64)] matching permuted weight rows.
__global__ __launch_bounds__(256) void k_agg(const float* __restrict__ xt,
        const int* __restrict__ cnt, const int2* __restrict__ bucket,
        const float* __restrict__ pe, float* __restrict__ U){
    int wave = threadIdx.x >> 6, lane = threadIdx.x & 63;
    int n = blockIdx.x * 4 + wave;
    if (n >= NN) return;
    int len = cnt[n];
    if (len > CAP) len = CAP;
    const int2* b = bucket + (size_t)n * CAP;
    float pr0 = pe[n * 3 + 0], pr1 = pe[n * 3 + 1], pr2 = pe[n * 3 + 2];
    float accA = 0.f, sumw = 0.f;
    float a0 = 0.f, a1 = 0.f, a2 = 0.f, a3 = 0.f, a4 = 0.f, a5 = 0.f;
    for (int s = 0; s < len; ++s){
        int2 m = b[s];
        int col = m.x;
        float w = __int_as_float(m.y);
        float d0 = pe[col * 3 + 0] - pr0;
        float d1 = pe[col * 3 + 1] - pr1;
        float d2 = pe[col * 3 + 2] - pr2;
        float xv = xt[(size_t)col * HH + lane];
        sumw += w;
        accA += w * xv;
        a0 += fmaxf(d0, 0.f) * xv;  a3 += fmaxf(-d0, 0.f) * xv;
        a1 += fmaxf(d1, 0.f) * xv;  a4 += fmaxf(-d1, 0.f) * xv;
        a2 += fmaxf(d2, 0.f) * xv;  a5 += fmaxf(-d2, 0.f) * xv;
    }
    float di = (sumw == 0.f) ? 0.f : 1.f / sumw;
    float* ur = U + (size_t)n * 448;
    ur[lane]            = accA * di;
    ur[64 + 0*64 + lane] = a0 * di;
    ur[64 + 1*64 + lane] = a1 * di;
    ur[64 + 2*64 + lane] = a2 * di;
    ur[64 + 3*64 + lane] = a3 * di;
    ur[64 + 4*64 + lane] = a4 * di;
    ur[64 + 5*64 + lane] = a5 * di;
}

// Fused fusion-GEMM + finalize: h_pre = [xt | U] @ fW + fb (K=512, chunked LDS),
// hp = lrelu, out (+)= hp * softmax_p(d) + hb.  Weight rows read in permuted order
// so that U's [avg | j-major dir] layout matches h_cat's column ordering.
__global__ __launch_bounds__(256) void k_fuse(const float* __restrict__ xt,
        const float* __restrict__ U, const float* __restrict__ fW,
        const float* __restrict__ fb, const float* __restrict__ dmat,
        const float* __restrict__ hb, int p, int first, float* __restrict__ out){
    __shared__ float xs[32][68];
    int nb = blockIdx.x * 32;
    int t = threadIdx.x;
    int lane = t & 63, wave = t >> 6, nw = wave * 8;
    float acc[8];
    float bb = fb[lane];
    #pragma unroll
    for (int i = 0; i < 8; ++i) acc[i] = bb;
    #pragma unroll
    for (int c = 0; c < 8; ++c){
        __syncthreads();
        {
            int r = t >> 3, f0 = (t & 7) * 8;
            int n = nb + r;
            float4 v0 = make_float4(0.f,0.f,0.f,0.f), v1 = v0;
            if (n < NN){
                const float* src = (c == 0) ? (xt + (size_t)n * HH + f0)
                                            : (U + (size_t)n * 448 + (c - 1) * 64 + f0);
                v0 = *reinterpret_cast<const float4*>(src);
                v1 = *reinterpret_cast<const float4*>(src + 4);
            }
            *reinterpret_cast<float4*>(&xs[r][f0]) = v0;
            *reinterpret_cast<float4*>(&xs[r][f0 + 4]) = v1;
        }
        __syncthreads();
        #pragma unroll
        for (int kk = 0; kk < 16; ++kk){
            float wv[4];
            #pragma unroll
            for (int u = 0; u < 4; ++u){
                int q = c * 64 + kk * 4 + u;
                int kref = (q < 128) ? q : (128 + ((q - 128) & 63) * 6 + ((q - 128) >> 6));
                wv[u] = fW[(size_t)kref * HH + lane];
            }
            #pragma unroll
            for (int i = 0; i < 8; ++i){
                float4 xv = *reinterpret_cast<const float4*>(&xs[nw + i][kk * 4]);
                acc[i] += xv.x * wv[0] + xv.y * wv[1] + xv.z * wv[2] + xv.w * wv[3];
            }
        }
    }
    float d0 = dmat[lane], d1 = dmat[64 + lane], d2 = dmat[128 + lane];
    float mx = fmaxf(d0, fmaxf(d1, d2));
    float e0 = expf(d0 - mx), e1 = expf(d1 - mx), e2 = expf(d2 - mx);
    float dw = ((p == 0) ? e0 : (p == 1) ? e1 : e2) / (e0 + e1 + e2);
    float hbv = hb[lane];
    #pragma unroll
    for (int i = 0; i < 8; ++i){
        int n = nb + nw + i;
        if (n < NN){
            float hp = lrelu(acc[i]);
            float v = hp * dw + hbv;
            size_t oi = (size_t)n * HH + lane;
            out[oi] = first ? v : (out[oi] + v);
        }
    }
}

// per-graph column sums/sumsq via per-wave run-length segments + atomics.
__global__ void k_stats2(const float* __restrict__ X, const int* __restrict__ batch,
                         float* __restrict__ sums, float* __restrict__ sumsq){
    int wave = threadIdx.x >> 6, lane = threadIdx.x & 63;
    int n0 = (blockIdx.x * 4 + wave) * 64;
    if (n0 >= NN) return;
    int n1 = n0 + 64; if (n1 > NN) n1 = NN;
    float s = 0.f, q = 0.f;
    int gcur = batch[n0];
    for (int n = n0; n < n1; ++n){
        int g = batch[n];
        if (g != gcur){
            atomicAdd(&sums[gcur * 64 + lane], s);
            atomicAdd(&sumsq[gcur * 64 + lane], q);
            s = 0.f; q = 0.f; gcur = g;
        }
        float v = X[(size_t)n * 64 + lane];
        s += v; q += v * v;
    }
    atomicAdd(&sums[gcur * 64 + lane], s);
    atomicAdd(&sumsq[gcur * 64 + lane], q);
}

// graph-norm + leaky_relu, in place.  var = E[x^2] - mean^2 * ms * (2 - ms)
__global__ void k_gnorm(float* __restrict__ X, const int* __restrict__ batch,
                        const int* __restrict__ gstart,
                        const float* __restrict__ sums, const float* __restrict__ sumsq,
                        const float* __restrict__ w, const float* __restrict__ b,
                        const float* __restrict__ ms){
    int gid = blockIdx.x * blockDim.x + threadIdx.x;
    if (gid >= NN * HH) return;
    int n = gid >> 6, o = gid & 63;
    int g = batch[n];
    float cnt = fmaxf((float)(gstart[g + 1] - gstart[g]), 1.f);
    float mean = sums[g * 64 + o] / cnt;
    float ex2 = sumsq[g * 64 + o] / cnt;
    float m = ms[o];
    float var = ex2 - mean * mean * m * (2.f - m);
    float v = (X[gid] - mean * m) * (1.f / sqrtf(var + 1e-5f)) * w[o] + b[o];
    X[gid] = lrelu(v);
}

// gate = sigmoid([h,fx] @ gate_W + gate_b); X = gate*h + (1-gate)*fx + X
__global__ __launch_bounds__(256) void k_gate2(const float* __restrict__ h,
                       const float* __restrict__ fx, const float* __restrict__ gW,
                       const float* __restrict__ gb, float* __restrict__ X){
    __shared__ float hs[32][HH];
    __shared__ float fs[32][HH];
    int nb = blockIdx.x * 32;
    int t = threadIdx.x;
    #pragma unroll
    for (int i = 0; i < 2; ++i){
        int idx = t + 256 * i;
        int r = idx >> 4, c4 = idx & 15;
        int n = nb + r;
        float4 vh = make_float4(0.f, 0.f, 0.f, 0.f);
        float4 vf = make_float4(0.f, 0.f, 0.f, 0.f);
        if (n < NN){
            vh = *reinterpret_cast<const float4*>(h  + (size_t)n * HH + c4 * 4);
            vf = *reinterpret_cast<const float4*>(fx + (size_t)n * HH + c4 * 4);
        }
        *reinterpret_cast<float4*>(&hs[r][c4 * 4]) = vh;
        *reinterpret_cast<float4*>(&fs[r][c4 * 4]) = vf;
    }
    __syncthreads();
    int lane = t & 63, wave = t >> 6, nw = wave * 8;
    float acc[8];
    float bb = gb[lane];
    #pragma unroll
    for (int i = 0; i < 8; ++i) acc[i] = bb;
    #pragma unroll 2
    for (int k = 0; k < HH; ++k){
        float w1 = gW[(size_t)k * HH + lane];
        float w2 = gW[(size_t)(64 + k) * HH + lane];
        #pragma unroll
        for (int i = 0; i < 8; ++i) acc[i] += hs[nw + i][k] * w1 + fs[nw + i][k] * w2;
    }
    #pragma unroll
    for (int i = 0; i < 8; ++i){
        int n = nb + nw + i;
        if (n < NN){
            float gt = 1.f / (1.f + expf(-acc[i]));
            float hv = hs[nw + i][lane];
            float fv = fs[nw + i][lane];
            size_t idx = (size_t)n * HH + lane;
            X[idx] = gt * hv + (1.f - gt) * fv + X[idx];
        }
    }
}

__global__ void k_finalout(const float* __restrict__ sums, const int* __restrict__ gstart,
                           float* __restrict__ out){
    int gid = blockIdx.x * blockDim.x + threadIdx.x;
    if (gid >= GG * HH) return;
    int g = gid >> 6;
    float cnt = fmaxf((float)(gstart[g + 1] - gstart[g]), 1.f);
    out[gid] = sums[gid] / cnt;
}

extern "C" void kernel_launch(void* const* d_in, const int* in_sizes, int n_in,
                              void* d_out, int out_size, void* d_ws, size_t ws_size,
                              hipStream_t stream) {
    const float* x_in   = (const float*)d_in[0];
    const float* pe     = (const float*)d_in[1];
    const int*   batch  = (const int*)d_in[2];
    const int*   uei    = (const int*)d_in[3];
    const float* uew    = (const float*)d_in[4];
    const int*   fei    = (const int*)d_in[5];
    const float* few    = (const float*)d_in[6];
    const float* emb_W  = (const float*)d_in[7];
    const float* emb_b  = (const float*)d_in[8];
    const float* S_lin_W= (const float*)d_in[9];
    const float* S_lin_b= (const float*)d_in[10];
    const float* S_d    = (const float*)d_in[11];
    const float* S_hb   = (const float*)d_in[12];
    const float* S_fW   = (const float*)d_in[13];
    const float* S_fb   = (const float*)d_in[14];
    const float* F_lin_W= (const float*)d_in[15];
    const float* F_lin_b= (const float*)d_in[16];
    const float* F_d    = (const float*)d_in[17];
    const float* F_hb   = (const float*)d_in[18];
    const float* F_fW   = (const float*)d_in[19];
    const float* F_fb   = (const float*)d_in[20];
    const float* nS_w   = (const float*)d_in[21];
    const float* nS_b   = (const float*)d_in[22];
    const float* nS_m   = (const float*)d_in[23];
    const float* nF_w   = (const float*)d_in[24];
    const float* nF_b   = (const float*)d_in[25];
    const float* nF_m   = (const float*)d_in[26];
    const float* gate_W = (const float*)d_in[27];
    const float* gate_b = (const float*)d_in[28];
    float* out = (float*)d_out;

    size_t off = 0;
    auto alloc = [&](size_t bytes)->void*{
        void* p = (char*)d_ws + off;
        off += (bytes + 255) & ~(size_t)255;
        return p;
    };
    float* xbuf   = (float*)alloc((size_t)NN * HH * 4);
    float* hbuf   = (float*)alloc((size_t)NN * HH * 4);
    float* fxbuf  = (float*)alloc((size_t)NN * HH * 4);
    float* xt     = (float*)alloc((size_t)NN * HH * 4);
    float* U      = (float*)alloc((size_t)NN * 448 * 4);
    int*   cnt    = (int*)  alloc((size_t)6 * NN * 4);
    int2*  bucket = (int2*) alloc((size_t)6 * NN * CAP * 8);
    int*   gstart = (int*)  alloc((GG + 1) * 4);
    float* sums   = (float*)alloc(GG * HH * 4);
    float* sumsq  = (float*)alloc(GG * HH * 4);

    const int BLK = 256;
    const int gridNH = (NN * HH) / BLK;          // 12500
    const int gridN32 = (NN + 31) / 32;          // 1563
    const int gridRow = (NN + 3) / 4;            // 12500
    const int gridStats = (NN + 255) / 256;      // 196
    const int gridEdges = (2 * PP * EE + BLK - 1) / BLK;

    k_bounds<<<1, 64, 0, stream>>>(batch, gstart);
    hipMemsetAsync(cnt, 0, (size_t)6 * NN * 4, stream);
    k_fill2<<<gridEdges, BLK, 0, stream>>>(uei, uew, fei, few, cnt, bucket);
    k_lin64<<<gridN32, BLK, 0, stream>>>(x_in, emb_W, emb_b, xbuf);

    // which: 0..2 = u-edge hops, 3..5 = f-edge hops
    auto opdmp = [&](const float* xin, float* outb, int whichBase,
                     const float* linW, const float* linb,
                     const float* dmat, const float* hbias, const float* fW, const float* fb){
        k_lin64<<<gridN32, BLK, 0, stream>>>(xin, linW, linb, xt);
        for (int p = 0; p < PP; ++p){
            int which = whichBase + p;
            k_agg<<<gridRow, BLK, 0, stream>>>(xt,
                    cnt + (size_t)which * NN, bucket + (size_t)which * NN * CAP, pe, U);
            k_fuse<<<gridN32, BLK, 0, stream>>>(xt, U, fW + (size_t)p * 512 * HH,
                    fb + p * HH, dmat, hbias + p * HH, p, (p == 0) ? 1 : 0, outb);
        }
    };
    auto gnorm = [&](float* X, const float* w, const float* b, const float* ms){
        hipMemsetAsync(sums, 0, GG * HH * 4, stream);
        hipMemsetAsync(sumsq, 0, GG * HH * 4, stream);
        k_stats2<<<gridStats, BLK, 0, stream>>>(X, batch, sums, sumsq);
        k_gnorm<<<gridNH, BLK, 0, stream>>>(X, batch, gstart, sums, sumsq, w, b, ms);
    };

    for (int i = 0; i < LL; ++i){
        opdmp(xbuf, hbuf, 0,
              S_lin_W + (size_t)i * HH * HH, S_lin_b + (size_t)i * HH,
              S_d + (size_t)i * PP * HH, S_hb + (size_t)i * PP * HH,
              S_fW + (size_t)i * PP * 512 * HH, S_fb + (size_t)i * PP * HH);
        gnorm(hbuf, nS_w + (size_t)i * HH, nS_b + (size_t)i * HH, nS_m + (size_t)i * HH);
        opdmp(hbuf, fxbuf, PP,
              F_lin_W + (size_t)i * HH * HH, F_lin_b + (size_t)i * HH,
              F_d + (size_t)i * PP * HH, F_hb + (size_t)i * PP * HH,
              F_fW + (size_t)i * PP * 512 * HH, F_fb + (size_t)i * PP * HH);
        gnorm(fxbuf, nF_w + (size_t)i * HH, nF_b + (size_t)i * HH, nF_m + (size_t)i * HH);
        k_gate2<<<gridN32, BLK, 0, stream>>>(hbuf, fxbuf, gate_W, gate_b, xbuf);
    }

    hipMemsetAsync(sums, 0, GG * HH * 4, stream);
    hipMemsetAsync(sumsq, 0, GG * HH * 4, stream);
    k_stats2<<<gridStats, BLK, 0, stream>>>(xbuf, batch, sums, sumsq);
    k_finalout<<<(GG * HH + BLK - 1) / BLK, BLK, 0, stream>>>(sums, gstart, out);
}

// Round 7
// 2060.964 us; speedup vs baseline: 51.2060x; 51.2060x over previous
//
#include <hip/hip_runtime.h>
#include <cstdint>
#include <cstddef>

#define NN 50000
#define EE 300000
#define HH 64
#define PP 3
#define GG 50
#define LL 2
#define CAP 32
#define SLOPE 0.01f

__device__ __forceinline__ float lrelu(float x){ return x >= 0.f ? x : SLOPE*x; }

// gstart[g] = first index i with batch[i] >= g (batch sorted); gstart[GG] = NN
__global__ void k_bounds(const int* __restrict__ batch, int* __restrict__ gstart){
    int g = threadIdx.x;
    if (g > GG) return;
    int lo = 0, hi = NN;
    while (lo < hi){ int mid = (lo + hi) >> 1; if (batch[mid] < g) lo = mid + 1; else hi = mid; }
    gstart[g] = lo;
}

// Single-pass bucket-CSR fill over all 6 edge sets.
__global__ void k_fill2(const int* __restrict__ uei, const float* __restrict__ uew,
                        const int* __restrict__ fei, const float* __restrict__ few,
                        int* __restrict__ cnt, int2* __restrict__ bucket){
    int t = blockIdx.x * blockDim.x + threadIdx.x;
    if (t >= 2 * PP * EE) return;
    int which = t / EE;
    int e = t - which * EE;
    const int* ei; const float* ew; int p;
    if (which < PP){ ei = uei; ew = uew; p = which; }
    else           { ei = fei; ew = few; p = which - PP; }
    int row = ei[(size_t)(p * 2 + 0) * EE + e];
    int col = ei[(size_t)(p * 2 + 1) * EE + e];
    float w = ew[(size_t)p * EE + e];
    int slot = atomicAdd(cnt + (size_t)which * NN + row, 1);
    if (slot < CAP)
        bucket[((size_t)which * NN + row) * CAP + slot] = make_int2(col, __float_as_int(w));
}

// Permute fusion weights once per hop: Wp[q][o] = fW[kref(q)][o].
// q order: [xt(64) | avg(64) | dir j-major: j*64+h], kref: [q | q | 128 + h*6 + j]
__global__ void k_wperm(const float* __restrict__ fW, float* __restrict__ Wp){
    int gid = blockIdx.x * blockDim.x + threadIdx.x;   // 512*64
    int q = gid >> 6, o = gid & 63;
    int kref;
    if (q < 128) kref = q;
    else { int r = q - 128; kref = 128 + (r & 63) * 6 + (r >> 6); }
    Wp[gid] = fW[(size_t)kref * HH + o];
}

// Register-blocked (N,64)@(64,64): 32 nodes/block, 4 waves, 8 nodes/wave, lane owns 1 column.
__global__ __launch_bounds__(256) void k_lin64(const float* __restrict__ X,
                       const float* __restrict__ W, const float* __restrict__ b,
                       float* __restrict__ out){
    __shared__ float xs[32][HH];
    int nb = blockIdx.x * 32;
    int t = threadIdx.x;
    #pragma unroll
    for (int i = 0; i < 2; ++i){
        int idx = t + 256 * i;
        int r = idx >> 4, c4 = idx & 15;
        int n = nb + r;
        float4 v = make_float4(0.f, 0.f, 0.f, 0.f);
        if (n < NN) v = *reinterpret_cast<const float4*>(X + (size_t)n * HH + c4 * 4);
        *reinterpret_cast<float4*>(&xs[r][c4 * 4]) = v;
    }
    __syncthreads();
    int lane = t & 63, wave = t >> 6, nw = wave * 8;
    float acc[8];
    float bb = b[lane];
    #pragma unroll
    for (int i = 0; i < 8; ++i) acc[i] = bb;
    #pragma unroll 2
    for (int k = 0; k < HH; ++k){
        float wv = W[(size_t)k * HH + lane];
        #pragma unroll
        for (int i = 0; i < 8; ++i) acc[i] += xs[nw + i][k] * wv;
    }
    #pragma unroll
    for (int i = 0; i < 8; ++i){
        int n = nb + nw + i;
        if (n < NN) out[(size_t)n * HH + lane] = acc[i];
    }
}

// Per-hop aggregation: wave per node; gather x_t[col] per edge; 7 accumulators.
// U row layout (448): [avg(64) | j=0..5: dir_j(64)]
__global__ __launch_bounds__(256) void k_agg(const float* __restrict__ xt,
        const int* __restrict__ cnt, const int2* __restrict__ bucket,
        const float* __restrict__ pe, float* __restrict__ U){
    int wave = threadIdx.x >> 6, lane = threadIdx.x & 63;
    int n = blockIdx.x * 4 + wave;
    if (n >= NN) return;
    int len = cnt[n];
    if (len > CAP) len = CAP;
    const int2* b = bucket + (size_t)n * CAP;
    float pr0 = pe[n * 3 + 0], pr1 = pe[n * 3 + 1], pr2 = pe[n * 3 + 2];
    float accA = 0.f, sumw = 0.f;
    float a0 = 0.f, a1 = 0.f, a2 = 0.f, a3 = 0.f, a4 = 0.f, a5 = 0.f;
    for (int s = 0; s < len; ++s){
        int2 m = b[s];
        int col = m.x;
        float w = __int_as_float(m.y);
        float d0 = pe[col * 3 + 0] - pr0;
        float d1 = pe[col * 3 + 1] - pr1;
        float d2 = pe[col * 3 + 2] - pr2;
        float xv = xt[(size_t)col * HH + lane];
        sumw += w;
        accA += w * xv;
        a0 += fmaxf(d0, 0.f) * xv;  a3 += fmaxf(-d0, 0.f) * xv;
        a1 += fmaxf(d1, 0.f) * xv;  a4 += fmaxf(-d1, 0.f) * xv;
        a2 += fmaxf(d2, 0.f) * xv;  a5 += fmaxf(-d2, 0.f) * xv;
    }
    float di = (sumw == 0.f) ? 0.f : 1.f / sumw;
    float* ur = U + (size_t)n * 448;
    ur[lane]             = accA * di;
    ur[64 + 0*64 + lane] = a0 * di;
    ur[64 + 1*64 + lane] = a1 * di;
    ur[64 + 2*64 + lane] = a2 * di;
    ur[64 + 3*64 + lane] = a3 * di;
    ur[64 + 4*64 + lane] = a4 * di;
    ur[64 + 5*64 + lane] = a5 * di;
}

// Fused fusion-GEMM + finalize: h_pre = [xt|U] @ Wp + fb (K=512, 8 LDS chunks),
// hp = lrelu, out (+)= hp * softmax_p(d) + hb.  Wp is pre-permuted -> linear reads.
__global__ __launch_bounds__(256) void k_fuse(const float* __restrict__ xt,
        const float* __restrict__ U, const float* __restrict__ Wp,
        const float* __restrict__ fb, const float* __restrict__ dmat,
        const float* __restrict__ hb, int p, int first, float* __restrict__ out){
    __shared__ float xs[32][68];
    int nb = blockIdx.x * 32;
    int t = threadIdx.x;
    int lane = t & 63, wave = t >> 6, nw = wave * 8;
    float acc[8];
    float bb = fb[lane];
    #pragma unroll
    for (int i = 0; i < 8; ++i) acc[i] = bb;
    for (int c = 0; c < 8; ++c){
        __syncthreads();
        {
            int r = t >> 3, f0 = (t & 7) * 8;
            int n = nb + r;
            float4 v0 = make_float4(0.f,0.f,0.f,0.f), v1 = v0;
            if (n < NN){
                const float* src = (c == 0) ? (xt + (size_t)n * HH + f0)
                                            : (U + (size_t)n * 448 + (size_t)(c - 1) * 64 + f0);
                v0 = *reinterpret_cast<const float4*>(src);
                v1 = *reinterpret_cast<const float4*>(src + 4);
            }
            *reinterpret_cast<float4*>(&xs[r][f0]) = v0;
            *reinterpret_cast<float4*>(&xs[r][f0 + 4]) = v1;
        }
        __syncthreads();
        const float* wp = Wp + (size_t)c * 64 * 64 + lane;
        #pragma unroll 8
        for (int kk = 0; kk < 64; ++kk){
            float wv = wp[kk * 64];
            #pragma unroll
            for (int i = 0; i < 8; ++i) acc[i] += xs[nw + i][kk] * wv;
        }
    }
    float d0 = dmat[lane], d1 = dmat[64 + lane], d2 = dmat[128 + lane];
    float mx = fmaxf(d0, fmaxf(d1, d2));
    float e0 = expf(d0 - mx), e1 = expf(d1 - mx), e2 = expf(d2 - mx);
    float dw = ((p == 0) ? e0 : (p == 1) ? e1 : e2) / (e0 + e1 + e2);
    float hbv = hb[lane];
    #pragma unroll
    for (int i = 0; i < 8; ++i){
        int n = nb + nw + i;
        if (n < NN){
            float hp = lrelu(acc[i]);
            float v = hp * dw + hbv;
            size_t oi = (size_t)n * HH + lane;
            out[oi] = first ? v : (out[oi] + v);
        }
    }
}

// per-graph column sums/sumsq via per-wave run-length segments + atomics.
__global__ void k_stats2(const float* __restrict__ X, const int* __restrict__ batch,
                         float* __restrict__ sums, float* __restrict__ sumsq){
    int wave = threadIdx.x >> 6, lane = threadIdx.x & 63;
    int n0 = (blockIdx.x * 4 + wave) * 64;
    if (n0 >= NN) return;
    int n1 = n0 + 64; if (n1 > NN) n1 = NN;
    float s = 0.f, q = 0.f;
    int gcur = batch[n0];
    for (int n = n0; n < n1; ++n){
        int g = batch[n];
        if (g != gcur){
            atomicAdd(&sums[gcur * 64 + lane], s);
            atomicAdd(&sumsq[gcur * 64 + lane], q);
            s = 0.f; q = 0.f; gcur = g;
        }
        float v = X[(size_t)n * 64 + lane];
        s += v; q += v * v;
    }
    atomicAdd(&sums[gcur * 64 + lane], s);
    atomicAdd(&sumsq[gcur * 64 + lane], q);
}

// graph-norm + leaky_relu, in place.  var = E[x^2] - mean^2 * ms * (2 - ms)
__global__ void k_gnorm(float* __restrict__ X, const int* __restrict__ batch,
                        const int* __restrict__ gstart,
                        const float* __restrict__ sums, const float* __restrict__ sumsq,
                        const float* __restrict__ w, const float* __restrict__ b,
                        const float* __restrict__ ms){
    int gid = blockIdx.x * blockDim.x + threadIdx.x;
    if (gid >= NN * HH) return;
    int n = gid >> 6, o = gid & 63;
    int g = batch[n];
    float cnt = fmaxf((float)(gstart[g + 1] - gstart[g]), 1.f);
    float mean = sums[g * 64 + o] / cnt;
    float ex2 = sumsq[g * 64 + o] / cnt;
    float m = ms[o];
    float var = ex2 - mean * mean * m * (2.f - m);
    float v = (X[gid] - mean * m) * (1.f / sqrtf(var + 1e-5f)) * w[o] + b[o];
    X[gid] = lrelu(v);
}

// gate = sigmoid([h,fx] @ gate_W + gate_b); X = gate*h + (1-gate)*fx + X
__global__ __launch_bounds__(256) void k_gate2(const float* __restrict__ h,
                       const float* __restrict__ fx, const float* __restrict__ gW,
                       const float* __restrict__ gb, float* __restrict__ X){
    __shared__ float hs[32][HH];
    __shared__ float fs[32][HH];
    int nb = blockIdx.x * 32;
    int t = threadIdx.x;
    #pragma unroll
    for (int i = 0; i < 2; ++i){
        int idx = t + 256 * i;
        int r = idx >> 4, c4 = idx & 15;
        int n = nb + r;
        float4 vh = make_float4(0.f, 0.f, 0.f, 0.f);
        float4 vf = make_float4(0.f, 0.f, 0.f, 0.f);
        if (n < NN){
            vh = *reinterpret_cast<const float4*>(h  + (size_t)n * HH + c4 * 4);
            vf = *reinterpret_cast<const float4*>(fx + (size_t)n * HH + c4 * 4);
        }
        *reinterpret_cast<float4*>(&hs[r][c4 * 4]) = vh;
        *reinterpret_cast<float4*>(&fs[r][c4 * 4]) = vf;
    }
    __syncthreads();
    int lane = t & 63, wave = t >> 6, nw = wave * 8;
    float acc[8];
    float bb = gb[lane];
    #pragma unroll
    for (int i = 0; i < 8; ++i) acc[i] = bb;
    #pragma unroll 2
    for (int k = 0; k < HH; ++k){
        float w1 = gW[(size_t)k * HH + lane];
        float w2 = gW[(size_t)(64 + k) * HH + lane];
        #pragma unroll
        for (int i = 0; i < 8; ++i) acc[i] += hs[nw + i][k] * w1 + fs[nw + i][k] * w2;
    }
    #pragma unroll
    for (int i = 0; i < 8; ++i){
        int n = nb + nw + i;
        if (n < NN){
            float gt = 1.f / (1.f + expf(-acc[i]));
            float hv = hs[nw + i][lane];
            float fv = fs[nw + i][lane];
            size_t idx = (size_t)n * HH + lane;
            X[idx] = gt * hv + (1.f - gt) * fv + X[idx];
        }
    }
}

__global__ void k_finalout(const float* __restrict__ sums, const int* __restrict__ gstart,
                           float* __restrict__ out){
    int gid = blockIdx.x * blockDim.x + threadIdx.x;
    if (gid >= GG * HH) return;
    int g = gid >> 6;
    float cnt = fmaxf((float)(gstart[g + 1] - gstart[g]), 1.f);
    out[gid] = sums[gid] / cnt;
}

extern "C" void kernel_launch(void* const* d_in, const int* in_sizes, int n_in,
                              void* d_out, int out_size, void* d_ws, size_t ws_size,
                              hipStream_t stream) {
    const float* x_in   = (const float*)d_in[0];
    const float* pe     = (const float*)d_in[1];
    const int*   batch  = (const int*)d_in[2];
    const int*   uei    = (const int*)d_in[3];
    const float* uew    = (const float*)d_in[4];
    const int*   fei    = (const int*)d_in[5];
    const float* few    = (const float*)d_in[6];
    const float* emb_W  = (const float*)d_in[7];
    const float* emb_b  = (const float*)d_in[8];
    const float* S_lin_W= (const float*)d_in[9];
    const float* S_lin_b= (const float*)d_in[10];
    const float* S_d    = (const float*)d_in[11];
    const float* S_hb   = (const float*)d_in[12];
    const float* S_fW   = (const float*)d_in[13];
    const float* S_fb   = (const float*)d_in[14];
    const float* F_lin_W= (const float*)d_in[15];
    const float* F_lin_b= (const float*)d_in[16];
    const float* F_d    = (const float*)d_in[17];
    const float* F_hb   = (const float*)d_in[18];
    const float* F_fW   = (const float*)d_in[19];
    const float* F_fb   = (const float*)d_in[20];
    const float* nS_w   = (const float*)d_in[21];
    const float* nS_b   = (const float*)d_in[22];
    const float* nS_m   = (const float*)d_in[23];
    const float* nF_w   = (const float*)d_in[24];
    const float* nF_b   = (const float*)d_in[25];
    const float* nF_m   = (const float*)d_in[26];
    const float* gate_W = (const float*)d_in[27];
    const float* gate_b = (const float*)d_in[28];
    float* out = (float*)d_out;

    size_t off = 0;
    auto alloc = [&](size_t bytes)->void*{
        void* p = (char*)d_ws + off;
        off += (bytes + 255) & ~(size_t)255;
        return p;
    };
    float* xbuf   = (float*)alloc((size_t)NN * HH * 4);
    float* hbuf   = (float*)alloc((size_t)NN * HH * 4);
    float* fxbuf  = (float*)alloc((size_t)NN * HH * 4);
    float* xt     = (float*)alloc((size_t)NN * HH * 4);
    float* U      = (float*)alloc((size_t)NN * 448 * 4);
    float* Wp     = (float*)alloc((size_t)512 * HH * 4);
    int*   cnt    = (int*)  alloc((size_t)6 * NN * 4);
    int2*  bucket = (int2*) alloc((size_t)6 * NN * CAP * 8);
    int*   gstart = (int*)  alloc((GG + 1) * 4);
    float* sums   = (float*)alloc(GG * HH * 4);
    float* sumsq  = (float*)alloc(GG * HH * 4);

    const int BLK = 256;
    const int gridNH = (NN * HH) / BLK;          // 12500
    const int gridN32 = (NN + 31) / 32;          // 1563
    const int gridRow = (NN + 3) / 4;            // 12500
    const int gridStats = (NN + 255) / 256;      // 196
    const int gridEdges = (2 * PP * EE + BLK - 1) / BLK;

    k_bounds<<<1, 64, 0, stream>>>(batch, gstart);
    hipMemsetAsync(cnt, 0, (size_t)6 * NN * 4, stream);
    k_fill2<<<gridEdges, BLK, 0, stream>>>(uei, uew, fei, few, cnt, bucket);
    k_lin64<<<gridN32, BLK, 0, stream>>>(x_in, emb_W, emb_b, xbuf);

    // which: 0..2 = u-edge hops, 3..5 = f-edge hops
    auto opdmp = [&](const float* xin, float* outb, int whichBase,
                     const float* linW, const float* linb,
                     const float* dmat, const float* hbias, const float* fW, const float* fb){
        k_lin64<<<gridN32, BLK, 0, stream>>>(xin, linW, linb, xt);
        for (int p = 0; p < PP; ++p){
            int which = whichBase + p;
            k_wperm<<<(512 * HH) / BLK, BLK, 0, stream>>>(fW + (size_t)p * 512 * HH, Wp);
            k_agg<<<gridRow, BLK, 0, stream>>>(xt,
                    cnt + (size_t)which * NN, bucket + (size_t)which * NN * CAP, pe, U);
            k_fuse<<<gridN32, BLK, 0, stream>>>(xt, U, Wp,
                    fb + p * HH, dmat, hbias + p * HH, p, (p == 0) ? 1 : 0, outb);
        }
    };
    auto gnorm = [&](float* X, const float* w, const float* b, const float* ms){
        hipMemsetAsync(sums, 0, GG * HH * 4, stream);
        hipMemsetAsync(sumsq, 0, GG * HH * 4, stream);
        k_stats2<<<gridStats, BLK, 0, stream>>>(X, batch, sums, sumsq);
        k_gnorm<<<gridNH, BLK, 0, stream>>>(X, batch, gstart, sums, sumsq, w, b, ms);
    };

    for (int i = 0; i < LL; ++i){
        opdmp(xbuf, hbuf, 0,
              S_lin_W + (size_t)i * HH * HH, S_lin_b + (size_t)i * HH,
              S_d + (size_t)i * PP * HH, S_hb + (size_t)i * PP * HH,
              S_fW + (size_t)i * PP * 512 * HH, S_fb + (size_t)i * PP * HH);
        gnorm(hbuf, nS_w + (size_t)i * HH, nS_b + (size_t)i * HH, nS_m + (size_t)i * HH);
        opdmp(hbuf, fxbuf, PP,
              F_lin_W + (size_t)i * HH * HH, F_lin_b + (size_t)i * HH,
              F_d + (size_t)i * PP * HH, F_hb + (size_t)i * PP * HH,
              F_fW + (size_t)i * PP * 512 * HH, F_fb + (size_t)i * PP * HH);
        gnorm(fxbuf, nF_w + (size_t)i * HH, nF_b + (size_t)i * HH, nF_m + (size_t)i * HH);
        k_gate2<<<gridN32, BLK, 0, stream>>>(hbuf, fxbuf, gate_W, gate_b, xbuf);
    }

    hipMemsetAsync(sums, 0, GG * HH * 4, stream);
    hipMemsetAsync(sumsq, 0, GG * HH * 4, stream);
    k_stats2<<<gridStats, BLK, 0, stream>>>(xbuf, batch, sums, sumsq);
    k_finalout<<<(GG * HH + BLK - 1) / BLK, BLK, 0, stream>>>(sums, gstart, out);
}